// Round 19
// baseline (885.906 us; speedup 1.0000x reference)
//
#include <hip/hip_runtime.h>

#define N_NODES   32000
#define N_EDGES   512000
#define IN_CH     128
#define HID       256
#define HEADS     8
#define D_HEAD    32
#define N_LAYERS  4
#define N_GRAPHS  64
#define P_CHUNK   16
#define MAX_SIDX  2048
#define N_SBLK    125      // N_NODES / 256

typedef unsigned short u16;
typedef __bf16 bf16x8 __attribute__((ext_vector_type(8)));
typedef float f32x4 __attribute__((ext_vector_type(4)));
typedef unsigned short u16x8 __attribute__((ext_vector_type(8)));
typedef _Float16 h16x2 __attribute__((ext_vector_type(2)));

__device__ __forceinline__ u16 f2bf(float x) {
    union { float f; unsigned int u; } v; v.f = x;
    unsigned int r = v.u + 0x7FFFu + ((v.u >> 16) & 1u);  // round-to-nearest-even
    return (u16)(r >> 16);
}
__device__ __forceinline__ float bf2f(u16 b) {
    union { unsigned int u; float f; } v; v.u = ((unsigned int)b) << 16;
    return v.f;
}
__device__ __forceinline__ u16 f2h(float x) {
    union { _Float16 h; u16 u; } v; v.h = (_Float16)x; return v.u;
}
__device__ __forceinline__ float h2f(u16 b) {
    union { u16 u; _Float16 h; } v; v.u = b; return (float)v.h;
}

// ---------------------------------------------------------------- CSR build
__global__ __launch_bounds__(256) void count_kernel(const int* __restrict__ ei,
                                                    int* __restrict__ deg) {
    int e = blockIdx.x * 256 + threadIdx.x;
    if (e < N_EDGES) atomicAdd(&deg[ei[N_EDGES + e]], 1);
}

// hierarchical scan stage 1: per-block (256 nodes) local exclusive scan + block sum
__global__ __launch_bounds__(256) void scan1_kernel(const int* __restrict__ deg,
                                                    int* __restrict__ indptr,
                                                    int* __restrict__ bsum) {
    __shared__ int wsum[4];
    int tid = threadIdx.x, lane = tid & 63, wave = tid >> 6;
    int i = blockIdx.x * 256 + tid;
    int v = deg[i];
    int x = v;
    #pragma unroll
    for (int off = 1; off < 64; off <<= 1) {
        int t = __shfl_up(x, off, 64);
        if (lane >= off) x += t;
    }
    if (lane == 63) wsum[wave] = x;
    __syncthreads();
    if (tid == 0) {
        int s = 0;
        #pragma unroll
        for (int w = 0; w < 4; ++w) { int t = wsum[w]; wsum[w] = s; s += t; }
        bsum[blockIdx.x] = s;
    }
    __syncthreads();
    indptr[i] = wsum[wave] + x - v;   // block-local exclusive prefix
}

// stage 2: single wave scans the 125 block sums -> exclusive block offsets
__global__ __launch_bounds__(64) void scan2_kernel(const int* __restrict__ bsum,
                                                   int* __restrict__ boff,
                                                   int* __restrict__ indptr) {
    int lane = threadIdx.x;
    int carry = 0;
    for (int base = 0; base < N_SBLK; base += 64) {
        int i = base + lane;
        int v = (i < N_SBLK) ? bsum[i] : 0;
        int x = v;
        #pragma unroll
        for (int off = 1; off < 64; off <<= 1) {
            int t = __shfl_up(x, off, 64);
            if (lane >= off) x += t;
        }
        if (i < N_SBLK) boff[i] = carry + x - v;
        carry += __shfl(x, 63, 64);
    }
    if (lane == 0) indptr[N_NODES] = carry;
}

// stage 3: add block offsets; produce final indptr and cursor
__global__ __launch_bounds__(256) void scan3_kernel(const int* __restrict__ boff,
                                                    int* __restrict__ indptr,
                                                    int* __restrict__ cursor) {
    int i = blockIdx.x * 256 + threadIdx.x;
    int val = indptr[i] + boff[blockIdx.x];
    indptr[i] = val;
    cursor[i] = val;
}

__global__ __launch_bounds__(256) void scatter_kernel(const int* __restrict__ ei,
                                                      int* __restrict__ cursor,
                                                      int* __restrict__ ssrc) {
    int e = blockIdx.x * 256 + threadIdx.x;
    if (e < N_EDGES) {
        int dst = ei[N_EDGES + e];
        int pos = atomicAdd(&cursor[dst], 1);
        ssrc[pos] = ei[e];
    }
}

// ------------------------------------------- degree-bucketed node permutation
// two-level build: ZERO global atomics. Within-bucket order is
// non-deterministic but each node's computation is self-contained with fixed
// edge order -> output bits unaffected.
__global__ __launch_bounds__(256) void hist1_kernel(const int* __restrict__ deg,
                                                    int* __restrict__ blkcnt) {
    __shared__ int hloc[64];
    int tid = threadIdx.x;
    if (tid < 64) hloc[tid] = 0;
    __syncthreads();
    int b = deg[blockIdx.x * 256 + tid]; if (b > 63) b = 63;
    atomicAdd(&hloc[b], 1);                      // LDS atomic
    __syncthreads();
    if (tid < 64) blkcnt[blockIdx.x * 64 + tid] = hloc[tid];
}

// one wave; lane = bucket. Coalesced independent loads (pipeline-friendly).
__global__ __launch_bounds__(64) void bscan_kernel(const int* __restrict__ blkcnt,
                                                   int* __restrict__ gbase) {
    int b = threadIdx.x;
    int tot = 0;
    #pragma unroll 5
    for (int blk = 0; blk < N_SBLK; ++blk) tot += blkcnt[blk * 64 + b];
    int x = tot;
    #pragma unroll
    for (int off = 1; off < 64; off <<= 1) {
        int t = __shfl_up(x, off, 64);
        if (b >= off) x += t;
    }
    int running = x - tot;                       // exclusive bucket base
    #pragma unroll 5
    for (int blk = 0; blk < N_SBLK; ++blk) {
        int c = blkcnt[blk * 64 + b];
        gbase[blk * 64 + b] = running;
        running += c;
    }
}

__global__ __launch_bounds__(256) void perm2_kernel(const int* __restrict__ deg,
                                                    const int* __restrict__ gbase,
                                                    int* __restrict__ perm) {
    __shared__ int cur[64];
    int tid = threadIdx.x;
    if (tid < 64) cur[tid] = gbase[blockIdx.x * 64 + tid];
    __syncthreads();
    int i = blockIdx.x * 256 + tid;
    int b = deg[i]; if (b > 63) b = 63;
    int pos = atomicAdd(&cur[b], 1);             // LDS atomic
    perm[pos] = i;
}

// ---------------------------------------------------------------- conversions
__global__ __launch_bounds__(256) void tob16_kernel(const float* __restrict__ src,
                                                    u16* __restrict__ dst, int n) {
    int i = blockIdx.x * 256 + threadIdx.x;
    if (i < n) dst[i] = f2bf(src[i]);
}

// builds wcat[l][1024][256] = concat(wq,wk,wv,wskip) rows (single bf16)
__global__ __launch_bounds__(256) void wcat_kernel(const float* __restrict__ wq,
                                                   const float* __restrict__ wk,
                                                   const float* __restrict__ wv,
                                                   const float* __restrict__ ws,
                                                   u16* __restrict__ hi) {
    int i = blockIdx.x * 256 + threadIdx.x;  // 4*1024*256 = 1048576 total
    int l = i >> 18;
    int rem = i & 262143;
    int r = rem >> 8, c = rem & 255;
    int seg = r >> 8, rr = r & 255;
    const float* w = seg == 0 ? wq : seg == 1 ? wk : seg == 2 ? wv : ws;
    hi[i] = f2bf(w[(size_t)l * 65536 + rr * 256 + c]);
}

__global__ __launch_bounds__(256) void bcat_kernel(const float* __restrict__ bq,
                                                   const float* __restrict__ bk,
                                                   const float* __restrict__ bv,
                                                   const float* __restrict__ bs,
                                                   float* __restrict__ bcat) {
    int i = blockIdx.x * 256 + threadIdx.x;  // 4096
    int l = i >> 10, r = i & 1023;
    int seg = r >> 8, rr = r & 255;
    const float* b = seg == 0 ? bq : seg == 1 ? bk : seg == 2 ? bv : bs;
    bcat[i] = b[l * 256 + rr];
}

// ---------------------------------------------------------------- pe MLP stage 1
__global__ __launch_bounds__(256) void pe1_kernel(const float* __restrict__ lpe,
                                                  const float* __restrict__ w1,
                                                  const float* __restrict__ b1,
                                                  u16* __restrict__ t1b) {
    __shared__ float l[16];
    int n = blockIdx.x, j = threadIdx.x;
    if (j < 16) l[j] = lpe[n * 16 + j];
    __syncthreads();
    float s = b1[j];
    #pragma unroll
    for (int kk = 0; kk < 16; ++kk) s += l[kk] * w1[j * 16 + kk];
    t1b[(size_t)n * HID + j] = f2bf(fmaxf(s, 0.0f));
}

// ---------------------------------------------------------------- MFMA GEMM
// C[M x N] = A_bf16[M x K] @ W_bf16[N x K]^T + bias, f32 accumulate.
// BM=128, BN=256, 8 waves (2 row x 4 col), wave tile 64x64 (4x4 frags).
// REGISTER-DIRECT operand loads: each wave loads its MFMA fragments straight
// from global (16 rows x 64B contiguous per fragment-load -> full 64B sectors,
// L2-served). NO LDS staging, NO barriers in the K-loop -> waves pipeline and
// overlap independently. LDS used only by the wide-store epilogue.
// MODE 0: C0 = val;  MODE 1: C0 += val;
// MODE 2 (QKVS, N=1024): col<256 -> qb (f16); 256..767 -> khv head-sliced f16;
//                        >=768 -> skipb (f32)
template <int MODE>
__global__ __launch_bounds__(512) void mgemm(const u16* __restrict__ A,
                                             const u16* __restrict__ Wh,
                                             const float* __restrict__ bias,
                                             int K,
                                             float* __restrict__ C0,
                                             u16* __restrict__ qb,
                                             u16* __restrict__ khv,
                                             float* __restrict__ skipb) {
    __shared__ __align__(16) float sC[32 * 268];     // epilogue only (34.3KB)
    const int tid = threadIdx.x;
    const int l = tid & 63, wid = tid >> 6;          // 8 waves
    const int wm = wid >> 2, wn = wid & 3;           // 2 x 4
    const int lr = l & 15, lc = l >> 4;
    const int r0 = blockIdx.y * 128;
    const int c0 = blockIdx.x * 256;

    f32x4 acc[4][4];
    #pragma unroll
    for (int m = 0; m < 4; ++m)
        #pragma unroll
        for (int n = 0; n < 4; ++n) acc[m][n] = (f32x4){0.f, 0.f, 0.f, 0.f};

    // per-lane base pointers: row (wm*64+m*16+lr) of A, row (c0+wn*64+n*16+lr) of W,
    // column offset lc*8 within each K-step.
    const u16* aBase = A  + (size_t)(r0 + wm * 64 + lr) * K + lc * 8;
    const u16* wBase = Wh + (size_t)(c0 + wn * 64 + lr) * K + lc * 8;
    const size_t rowStride = (size_t)16 * K;

    const int nstep = K >> 5;
    #pragma unroll 2
    for (int t = 0; t < nstep; ++t) {
        const int k0 = t * 32;
        bf16x8 a[4], wh[4];
        #pragma unroll
        for (int m = 0; m < 4; ++m)
            a[m] = *reinterpret_cast<const bf16x8*>(aBase + (size_t)m * rowStride + k0);
        #pragma unroll
        for (int n = 0; n < 4; ++n)
            wh[n] = *reinterpret_cast<const bf16x8*>(wBase + (size_t)n * rowStride + k0);
        #pragma unroll
        for (int m = 0; m < 4; ++m)
            #pragma unroll
            for (int n = 0; n < 4; ++n)
                acc[m][n] = __builtin_amdgcn_mfma_f32_16x16x32_bf16(a[m], wh[n], acc[m][n], 0, 0, 0);
    }

    // ---- epilogue: 4 row-group passes; full-row wide stores ----
    const int lrr = tid >> 4;                       // 0..31 local row (readout)
    const int cseg = (tid & 15) * 16;               // 16-col segment base
    #pragma unroll
    for (int m = 0; m < 4; ++m) {
        __syncthreads();
        #pragma unroll
        for (int n = 0; n < 4; ++n) {
            #pragma unroll
            for (int i = 0; i < 4; ++i) {
                int lro = wm * 16 + lc * 4 + i;
                sC[lro * 268 + wn * 64 + n * 16 + lr] = acc[m][n][i];
            }
        }
        __syncthreads();
        int row = r0 + (lrr >> 4) * 64 + m * 16 + (lrr & 15);
        int col = c0 + cseg;
        f32x4 v[4];
        #pragma unroll
        for (int s = 0; s < 4; ++s) {
            v[s] = *reinterpret_cast<const f32x4*>(&sC[lrr * 268 + cseg + s * 4]);
            v[s] += *reinterpret_cast<const f32x4*>(&bias[col + s * 4]);
        }
        if (MODE == 0) {
            float* p = &C0[(size_t)row * 256 + col];
            #pragma unroll
            for (int s = 0; s < 4; ++s) *reinterpret_cast<f32x4*>(p + s * 4) = v[s];
        } else if (MODE == 1) {
            float* p = &C0[(size_t)row * 256 + col];
            #pragma unroll
            for (int s = 0; s < 4; ++s) {
                f32x4 o = *reinterpret_cast<const f32x4*>(p + s * 4);
                *reinterpret_cast<f32x4*>(p + s * 4) = v[s] + o;
            }
        } else {
            if (col < 256) {
                u16x8 o0, o1;
                #pragma unroll
                for (int j = 0; j < 4; ++j) {
                    o0[j] = f2h(v[0][j]); o0[4 + j] = f2h(v[1][j]);
                    o1[j] = f2h(v[2][j]); o1[4 + j] = f2h(v[3][j]);
                }
                u16* p = &qb[(size_t)row * 256 + col];
                *reinterpret_cast<u16x8*>(p) = o0;
                *reinterpret_cast<u16x8*>(p + 8) = o1;
            } else if (col < 768) {
                int cc = col - (col < 512 ? 256 : 512);
                int hh = cc >> 5, ch = cc & 31;
                int vo = (col < 512) ? 0 : 32;
                u16x8 o0, o1;
                #pragma unroll
                for (int j = 0; j < 4; ++j) {
                    o0[j] = f2h(v[0][j]); o0[4 + j] = f2h(v[1][j]);
                    o1[j] = f2h(v[2][j]); o1[4 + j] = f2h(v[3][j]);
                }
                u16* p = &khv[((size_t)hh * N_NODES + row) * 64 + vo + ch];
                *reinterpret_cast<u16x8*>(p) = o0;
                *reinterpret_cast<u16x8*>(p + 8) = o1;
            } else {
                float* p = &skipb[(size_t)row * 256 + (col - 768)];
                #pragma unroll
                for (int s = 0; s < 4; ++s) *reinterpret_cast<f32x4*>(p + s * 4) = v[s];
            }
        }
    }
}

// ---------------------------------------------------------------- LayerNorm -> bf16
__global__ __launch_bounds__(256) void ln_kernel(const float* __restrict__ h,
                                                 const float* __restrict__ gw,
                                                 const float* __restrict__ bw,
                                                 u16* __restrict__ xnb) {
    int lane = threadIdx.x & 63, wave = threadIdx.x >> 6;
    int node = blockIdx.x * 4 + wave;
    float4 v = ((const float4*)(h + (size_t)node * HID))[lane];
    float s = v.x + v.y + v.z + v.w;
    #pragma unroll
    for (int off = 32; off; off >>= 1) s += __shfl_xor(s, off, 64);
    float mu = s * (1.0f / HID);
    float dx = v.x - mu, dy = v.y - mu, dz = v.z - mu, dw = v.w - mu;
    float q = dx * dx + dy * dy + dz * dz + dw * dw;
    #pragma unroll
    for (int off = 32; off; off >>= 1) q += __shfl_xor(q, off, 64);
    float inv = rsqrtf(q * (1.0f / HID) + 1e-5f);
    int c = lane * 4;
    float o0 = dx * inv * gw[c + 0] + bw[c + 0];
    float o1 = dy * inv * gw[c + 1] + bw[c + 1];
    float o2 = dz * inv * gw[c + 2] + bw[c + 2];
    float o3 = dw * inv * gw[c + 3] + bw[c + 3];
    uint2 pk;
    pk.x = (unsigned int)f2bf(o0) | ((unsigned int)f2bf(o1) << 16);
    pk.y = (unsigned int)f2bf(o2) | ((unsigned int)f2bf(o3) << 16);
    *reinterpret_cast<uint2*>(xnb + (size_t)node * HID + c) = pk;
}

// ---------------------------------------------------------------- fused edge attention
// one 4-lane group per (perm-node, head); degree-sorted perm -> groups in a
// wave have near-equal edge counts. Per-group LDS index staging. f16 k/v with
// fdot2 QK.
__global__ __launch_bounds__(256) void agg_kernel(const u16* __restrict__ qb,
                                                  const u16* __restrict__ khv,
                                                  const int* __restrict__ indptr,
                                                  const int* __restrict__ ssrc,
                                                  const int* __restrict__ perm,
                                                  float* __restrict__ outb) {
    __shared__ int sIdx[MAX_SIDX];
    __shared__ int loff_s[64];
    const float scale = 0.17677669529663687f;  // 1/sqrt(32)
    const int tid = threadIdx.x;
    const int g = tid >> 2;     // group 0..63
    const int j = tid & 3;      // channel quad (8 ch) within head
    const int h = blockIdx.x & 7;
    const int nb = (blockIdx.x >> 3) * 64;
    const int n = perm[nb + g];

    // block-local exclusive scan of the 64 node degrees (wave 0)
    if (tid < 64) {
        int pn = perm[nb + tid];
        int d = indptr[pn + 1] - indptr[pn];
        int x = d;
        #pragma unroll
        for (int off = 1; off < 64; off <<= 1) {
            int t = __shfl_up(x, off, 64);
            if (tid >= off) x += t;
        }
        loff_s[tid] = x - d;
    }
    __syncthreads();

    const int s0 = indptr[n], s1 = indptr[n + 1];
    const int dg = s1 - s0;
    const int myoff = loff_s[g];
    const bool staged = (myoff + dg) <= MAX_SIDX;
    if (staged) {
        for (int i = j; i < dg; i += 4)
            sIdx[myoff + i] = ssrc[s0 + i];
    }
    __syncthreads();

    u16x8 q8 = *reinterpret_cast<const u16x8*>(qb + (size_t)n * HID + h * 32 + j * 8);
    h16x2 qp[4];
    #pragma unroll
    for (int i = 0; i < 4; ++i)
        qp[i] = *(reinterpret_cast<const h16x2*>(&q8) + i);

    const int last = s1 - 1;
    const u16* base = khv + (size_t)h * N_NODES * 64 + j * 8;
    float acc[8] = {0.f, 0.f, 0.f, 0.f, 0.f, 0.f, 0.f, 0.f};
    float ssum = 0.f;

    if (s0 < s1) {
        const int nchunk = (dg + 3) >> 2;
        const int npair = (nchunk + 1) >> 1;
        int iA[4], iB[4];
        u16x8 kA[4], vA[4], kB[4], vB[4];
        #define LDIDX(e_, dst_) { int e2 = (e_) > last ? last : (e_); \
            dst_ = staged ? sIdx[myoff + (e2 - s0)] \
                          : __builtin_nontemporal_load(&ssrc[e2]); }
        #define QKDOT(kreg_, prod_) { \
            const h16x2* kp = reinterpret_cast<const h16x2*>(&kreg_); \
            prod_ = __builtin_amdgcn_fdot2(qp[0], kp[0], 0.0f, false); \
            prod_ = __builtin_amdgcn_fdot2(qp[1], kp[1], prod_, false); \
            prod_ = __builtin_amdgcn_fdot2(qp[2], kp[2], prod_, false); \
            prod_ = __builtin_amdgcn_fdot2(qp[3], kp[3], prod_, false); }
        #pragma unroll
        for (int i = 0; i < 4; ++i) LDIDX(s0 + i, iA[i]);
        #pragma unroll
        for (int i = 0; i < 4; ++i) {
            const u16* rp = base + (size_t)iA[i] * 64;
            kA[i] = *reinterpret_cast<const u16x8*>(rp);
            vA[i] = *reinterpret_cast<const u16x8*>(rp + 32);
        }
        #pragma unroll
        for (int i = 0; i < 4; ++i) LDIDX(s0 + 4 + i, iB[i]);
        int eb = s0;
        for (int pc = 0; pc < npair; ++pc) {
            #pragma unroll
            for (int i = 0; i < 4; ++i) {
                const u16* rp = base + (size_t)iB[i] * 64;
                kB[i] = *reinterpret_cast<const u16x8*>(rp);
                vB[i] = *reinterpret_cast<const u16x8*>(rp + 32);
            }
            #pragma unroll
            for (int i = 0; i < 4; ++i) {
                float prod;
                QKDOT(kA[i], prod);
                prod += __shfl_xor(prod, 1, 64);
                prod += __shfl_xor(prod, 2, 64);
                float p = (eb + i <= last) ? __expf(prod * scale) : 0.f;
                ssum += p;
                #pragma unroll
                for (int t = 0; t < 8; ++t) acc[t] += p * h2f(vA[i][t]);
            }
            eb += 4;
            #pragma unroll
            for (int i = 0; i < 4; ++i) LDIDX(eb + 4 + i, iA[i]);
            #pragma unroll
            for (int i = 0; i < 4; ++i) {
                const u16* rp = base + (size_t)iA[i] * 64;
                kA[i] = *reinterpret_cast<const u16x8*>(rp);
                vA[i] = *reinterpret_cast<const u16x8*>(rp + 32);
            }
            #pragma unroll
            for (int i = 0; i < 4; ++i) {
                float prod;
                QKDOT(kB[i], prod);
                prod += __shfl_xor(prod, 1, 64);
                prod += __shfl_xor(prod, 2, 64);
                float p = (eb + i <= last) ? __expf(prod * scale) : 0.f;
                ssum += p;
                #pragma unroll
                for (int t = 0; t < 8; ++t) acc[t] += p * h2f(vB[i][t]);
            }
            eb += 4;
            #pragma unroll
            for (int i = 0; i < 4; ++i) LDIDX(eb + 4 + i, iB[i]);
        }
        #undef QKDOT
        #undef LDIDX
    }

    float inv = 1.0f / fmaxf(ssum, 1e-16f);
    float* op = outb + (size_t)n * HID + h * 32 + j * 8;
    f32x4 o0 = {acc[0] * inv, acc[1] * inv, acc[2] * inv, acc[3] * inv};
    f32x4 o1 = {acc[4] * inv, acc[5] * inv, acc[6] * inv, acc[7] * inv};
    __builtin_nontemporal_store(o0, (f32x4*)op);
    __builtin_nontemporal_store(o1, (f32x4*)(op + 4));
}

// ------------------------------------------- beta gate + relu + residual (+ next LN)
template <bool DO_LN>
__global__ __launch_bounds__(256) void beta_kernel(const float* __restrict__ outb,
                                                   const float* __restrict__ skipb,
                                                   const float* __restrict__ wb,
                                                   const float* __restrict__ gw,
                                                   const float* __restrict__ bw,
                                                   float* __restrict__ h,
                                                   u16* __restrict__ xnb) {
    int lane = threadIdx.x & 63, wave = threadIdx.x >> 6;
    int node = blockIdx.x * 4 + wave;
    int c = lane * 4;
    float4 o  = ((const float4*)(outb  + (size_t)node * HID))[lane];
    float4 sk = ((const float4*)(skipb + (size_t)node * HID))[lane];
    float acc = o.x * wb[c + 0] + o.y * wb[c + 1] + o.z * wb[c + 2] + o.w * wb[c + 3]
              + sk.x * wb[HID + c + 0] + sk.y * wb[HID + c + 1]
              + sk.z * wb[HID + c + 2] + sk.w * wb[HID + c + 3]
              + (o.x - sk.x) * wb[2 * HID + c + 0] + (o.y - sk.y) * wb[2 * HID + c + 1]
              + (o.z - sk.z) * wb[2 * HID + c + 2] + (o.w - sk.w) * wb[2 * HID + c + 3];
    #pragma unroll
    for (int off = 32; off; off >>= 1) acc += __shfl_xor(acc, off, 64);
    float beta = 1.0f / (1.0f + __expf(-acc));
    float4 r = ((const float4*)(h + (size_t)node * HID))[lane];
    float4 out;
    out.x = fmaxf(beta * sk.x + (1.0f - beta) * o.x, 0.0f) + r.x;
    out.y = fmaxf(beta * sk.y + (1.0f - beta) * o.y, 0.0f) + r.y;
    out.z = fmaxf(beta * sk.z + (1.0f - beta) * o.z, 0.0f) + r.z;
    out.w = fmaxf(beta * sk.w + (1.0f - beta) * o.w, 0.0f) + r.w;
    ((float4*)(h + (size_t)node * HID))[lane] = out;

    if (DO_LN) {
        float s = out.x + out.y + out.z + out.w;
        #pragma unroll
        for (int off = 32; off; off >>= 1) s += __shfl_xor(s, off, 64);
        float mu = s * (1.0f / HID);
        float dx = out.x - mu, dy = out.y - mu, dz = out.z - mu, dw = out.w - mu;
        float qq = dx * dx + dy * dy + dz * dz + dw * dw;
        #pragma unroll
        for (int off = 32; off; off >>= 1) qq += __shfl_xor(qq, off, 64);
        float inv = rsqrtf(qq * (1.0f / HID) + 1e-5f);
        float o0 = dx * inv * gw[c + 0] + bw[c + 0];
        float o1 = dy * inv * gw[c + 1] + bw[c + 1];
        float o2 = dz * inv * gw[c + 2] + bw[c + 2];
        float o3 = dw * inv * gw[c + 3] + bw[c + 3];
        uint2 pk;
        pk.x = (unsigned int)f2bf(o0) | ((unsigned int)f2bf(o1) << 16);
        pk.y = (unsigned int)f2bf(o2) | ((unsigned int)f2bf(o3) << 16);
        *reinterpret_cast<uint2*>(xnb + (size_t)node * HID + c) = pk;
    }
}

// ---------------------------------------------------------------- pooling + final MLP
__global__ __launch_bounds__(128) void bounds_kernel(const int* __restrict__ batch,
                                                     int* __restrict__ gstart) {
    int g = threadIdx.x;
    if (g > N_GRAPHS) return;
    int lo = 0, hi = N_NODES;
    while (lo < hi) { int mid = (lo + hi) >> 1; if (batch[mid] < g) lo = mid + 1; else hi = mid; }
    gstart[g] = lo;
}

// stage 1: 16 chunks per graph, deterministic partials pxg[g][chunk][256]
__global__ __launch_bounds__(256) void pool_kernel(const float* __restrict__ h,
                                                   const int* __restrict__ gstart,
                                                   float* __restrict__ pxg) {
    int gb = blockIdx.x;                 // 0 .. N_GRAPHS*P_CHUNK-1
    int g = gb >> 4, cch = gb & (P_CHUNK - 1);
    int t = threadIdx.x;
    int s = gstart[g], e = gstart[g + 1];
    float acc = 0.0f;
    for (int i = s + cch; i < e; i += P_CHUNK)
        acc += __builtin_nontemporal_load(&h[(size_t)i * HID + t]);
    pxg[(size_t)gb * HID + t] = acc;
}

__global__ __launch_bounds__(256) void mlp_kernel(const float* __restrict__ pxg,
                                                  const int* __restrict__ gstart,
                                                  const float* __restrict__ w1,
                                                  const float* __restrict__ b1,
                                                  const float* __restrict__ w2,
                                                  const float* __restrict__ b2,
                                                  float* __restrict__ out) {
    __shared__ float xr[256];
    __shared__ float red[256];
    int g = blockIdx.x, t = threadIdx.x;
    float sum = 0.0f;
    #pragma unroll
    for (int c = 0; c < P_CHUNK; ++c)
        sum += pxg[((size_t)g * P_CHUNK + c) * HID + t];
    float cnt = (float)(gstart[g + 1] - gstart[g]);
    xr[t] = sum / fmaxf(cnt, 1.0f);
    __syncthreads();
    float s = b1[t];
    #pragma unroll 4
    for (int kk = 0; kk < 256; ++kk) s += xr[kk] * w1[t * 256 + kk];
    s = fmaxf(s, 0.0f);
    red[t] = s * w2[t];
    __syncthreads();
    for (int off = 128; off; off >>= 1) {
        if (t < off) red[t] += red[t + off];
        __syncthreads();
    }
    if (t == 0) out[g] = red[0] + b2[0];
}

// ---------------------------------------------------------------- host
extern "C" void kernel_launch(void* const* d_in, const int* in_sizes, int n_in,
                              void* d_out, int out_size, void* d_ws, size_t ws_size,
                              hipStream_t stream) {
    const float* x      = (const float*)d_in[0];
    const float* lpe    = (const float*)d_in[1];
    const float* pe_w1  = (const float*)d_in[2];
    const float* pe_b1  = (const float*)d_in[3];
    const float* pe_w2  = (const float*)d_in[4];
    const float* pe_b2  = (const float*)d_in[5];
    const float* emb_w  = (const float*)d_in[6];
    const float* emb_b  = (const float*)d_in[7];
    const float* ln_g   = (const float*)d_in[8];
    const float* ln_b   = (const float*)d_in[9];
    const float* wq     = (const float*)d_in[10];
    const float* bq     = (const float*)d_in[11];
    const float* wk     = (const float*)d_in[12];
    const float* bk     = (const float*)d_in[13];
    const float* wv     = (const float*)d_in[14];
    const float* bv     = (const float*)d_in[15];
    const float* wskip  = (const float*)d_in[16];
    const float* bskip  = (const float*)d_in[17];
    const float* wbeta  = (const float*)d_in[18];
    const float* mlp_w1 = (const float*)d_in[19];
    const float* mlp_b1 = (const float*)d_in[20];
    const float* mlp_w2 = (const float*)d_in[21];
    const float* mlp_b2 = (const float*)d_in[22];
    const int*   eidx   = (const int*)d_in[23];
    const int*   batch  = (const int*)d_in[24];

    char* w = (char*)d_ws;
    const size_t NH = (size_t)N_NODES * HID;
    float* h     = (float*)w;           w += NH * 4;
    float* skipb = (float*)w;           w += NH * 4;
    float* outb  = (float*)w;           w += NH * 4;
    float* pxg   = (float*)w;           w += (size_t)N_GRAPHS * P_CHUNK * HID * 4;
    u16* qb      = (u16*)w;             w += NH * 2;
    u16* xnb     = (u16*)w;             w += NH * 2;
    u16* khv     = (u16*)w;             w += (size_t)HEADS * N_NODES * 64 * 2;
    u16* xb      = (u16*)w;             w += (size_t)N_NODES * IN_CH * 2;
    u16* t1b     = (u16*)w;             w += NH * 2;
    u16* ehi     = (u16*)w;             w += 32768 * 2;
    u16* p2hi    = (u16*)w;             w += 65536 * 2;
    u16* wchi    = (u16*)w;             w += 1048576 * 2;
    float* bcat  = (float*)w;           w += 4096 * 4;
    int* deg     = (int*)w;             w += N_NODES * 4;
    int* indptr  = (int*)w;             w += (N_NODES + 1) * 4;
    int* cursor  = (int*)w;             w += N_NODES * 4;
    int* ssrc    = (int*)w;             w += N_EDGES * 4;
    int* gstart  = (int*)w;             w += (N_GRAPHS + 1) * 4;
    int* bsum    = (int*)w;             w += 128 * 4;
    int* boff    = (int*)w;             w += 128 * 4;
    int* blkcnt  = (int*)w;             w += N_SBLK * 64 * 4;
    int* gbase   = (int*)w;             w += N_SBLK * 64 * 4;
    int* perm    = (int*)w;             w += N_NODES * 4;

    // weight conversions (every call; deterministic)
    tob16_kernel<<<128, 256, 0, stream>>>(emb_w, ehi, 32768);
    tob16_kernel<<<256, 256, 0, stream>>>(pe_w2, p2hi, 65536);
    wcat_kernel<<<4096, 256, 0, stream>>>(wq, wk, wv, wskip, wchi);
    bcat_kernel<<<16, 256, 0, stream>>>(bq, bk, bv, bskip, bcat);
    tob16_kernel<<<16000, 256, 0, stream>>>(x, xb, N_NODES * IN_CH);

    // CSR by destination (hierarchical scan) + degree-bucketed permutation
    hipMemsetAsync(deg, 0, N_NODES * sizeof(int), stream);
    count_kernel<<<(N_EDGES + 255) / 256, 256, 0, stream>>>(eidx, deg);
    scan1_kernel<<<N_SBLK, 256, 0, stream>>>(deg, indptr, bsum);
    scan2_kernel<<<1, 64, 0, stream>>>(bsum, boff, indptr);
    scan3_kernel<<<N_SBLK, 256, 0, stream>>>(boff, indptr, cursor);
    scatter_kernel<<<(N_EDGES + 255) / 256, 256, 0, stream>>>(eidx, cursor, ssrc);
    hist1_kernel<<<N_SBLK, 256, 0, stream>>>(deg, blkcnt);
    bscan_kernel<<<1, 64, 0, stream>>>(blkcnt, gbase);
    perm2_kernel<<<N_SBLK, 256, 0, stream>>>(deg, gbase, perm);

    // h = x@emb_w^T + emb_b + pe_mlp(lpe)
    pe1_kernel<<<N_NODES, 256, 0, stream>>>(lpe, pe_w1, pe_b1, t1b);
    mgemm<0><<<dim3(1, 250), 512, 0, stream>>>(xb, ehi, emb_b, IN_CH, h, nullptr, nullptr, nullptr);
    mgemm<1><<<dim3(1, 250), 512, 0, stream>>>(t1b, p2hi, pe_b2, HID, h, nullptr, nullptr, nullptr);

    ln_kernel<<<N_NODES / 4, 256, 0, stream>>>(h, ln_g, ln_b, xnb);
    for (int l = 0; l < N_LAYERS; ++l) {
        mgemm<2><<<dim3(4, 250), 512, 0, stream>>>(xnb, wchi + (size_t)l * 262144,
                                                   bcat + l * 1024, HID,
                                                   nullptr, qb, khv, skipb);
        agg_kernel<<<(N_NODES / 64) * 8, 256, 0, stream>>>(qb, khv, indptr, ssrc, perm, outb);
        if (l < N_LAYERS - 1) {
            beta_kernel<true><<<N_NODES / 4, 256, 0, stream>>>(
                outb, skipb, wbeta + l * 3 * HID,
                ln_g + (l + 1) * HID, ln_b + (l + 1) * HID, h, xnb);
        } else {
            beta_kernel<false><<<N_NODES / 4, 256, 0, stream>>>(
                outb, skipb, wbeta + l * 3 * HID, nullptr, nullptr, h, nullptr);
        }
    }

    bounds_kernel<<<1, 128, 0, stream>>>(batch, gstart);
    pool_kernel<<<N_GRAPHS * P_CHUNK, 256, 0, stream>>>(h, gstart, pxg);
    mlp_kernel<<<N_GRAPHS, 256, 0, stream>>>(pxg, gstart, mlp_w1, mlp_b1, mlp_w2, mlp_b2, (float*)d_out);
}

// Round 20
// 716.363 us; speedup vs baseline: 1.2367x; 1.2367x over previous
//
#include <hip/hip_runtime.h>

#define N_NODES   32000
#define N_EDGES   512000
#define IN_CH     128
#define HID       256
#define HEADS     8
#define D_HEAD    32
#define N_LAYERS  4
#define N_GRAPHS  64
#define P_CHUNK   16
#define MAX_SIDX  2048
#define N_SBLK    125      // N_NODES / 256

typedef unsigned short u16;
typedef __bf16 bf16x8 __attribute__((ext_vector_type(8)));
typedef float f32x4 __attribute__((ext_vector_type(4)));
typedef unsigned short u16x8 __attribute__((ext_vector_type(8)));
typedef _Float16 h16x2 __attribute__((ext_vector_type(2)));

__device__ __forceinline__ u16 f2bf(float x) {
    union { float f; unsigned int u; } v; v.f = x;
    unsigned int r = v.u + 0x7FFFu + ((v.u >> 16) & 1u);  // round-to-nearest-even
    return (u16)(r >> 16);
}
__device__ __forceinline__ float bf2f(u16 b) {
    union { unsigned int u; float f; } v; v.u = ((unsigned int)b) << 16;
    return v.f;
}
__device__ __forceinline__ u16 f2h(float x) {
    union { _Float16 h; u16 u; } v; v.h = (_Float16)x; return v.u;
}
__device__ __forceinline__ float h2f(u16 b) {
    union { u16 u; _Float16 h; } v; v.u = b; return (float)v.h;
}

// async global->LDS, 16B per lane; lds dest = wave-uniform base + lane*16
__device__ __forceinline__ void gll16(const u16* g, u16* l) {
    __builtin_amdgcn_global_load_lds(
        (const __attribute__((address_space(1))) unsigned int*)g,
        (__attribute__((address_space(3))) unsigned int*)l, 16, 0, 0);
}

__device__ __forceinline__ int lbound_batch(const int* __restrict__ batch, int g) {
    int lo = 0, hi = N_NODES;
    while (lo < hi) { int mid = (lo + hi) >> 1; if (batch[mid] < g) lo = mid + 1; else hi = mid; }
    return lo;
}

// ---------------------------------------------------------------- fused prep
// all input conversions in ONE dispatch (was 5)
__global__ __launch_bounds__(256) void prep_kernel(
    const float* __restrict__ x, const float* __restrict__ emb_w,
    const float* __restrict__ pe_w2,
    const float* __restrict__ wq, const float* __restrict__ wk,
    const float* __restrict__ wv, const float* __restrict__ ws,
    const float* __restrict__ bq, const float* __restrict__ bk,
    const float* __restrict__ bv, const float* __restrict__ bs,
    u16* __restrict__ xb, u16* __restrict__ ehi, u16* __restrict__ p2hi,
    u16* __restrict__ wchi, float* __restrict__ bcat) {
    int i = blockIdx.x * 256 + threadIdx.x;
    if (i < 4096000) { xb[i] = f2bf(x[i]); return; }
    i -= 4096000;
    if (i < 32768) { ehi[i] = f2bf(emb_w[i]); return; }
    i -= 32768;
    if (i < 65536) { p2hi[i] = f2bf(pe_w2[i]); return; }
    i -= 65536;
    if (i < 1048576) {
        int l = i >> 18; int rem = i & 262143;
        int r = rem >> 8, c = rem & 255;
        int seg = r >> 8, rr = r & 255;
        const float* w = seg == 0 ? wq : seg == 1 ? wk : seg == 2 ? wv : ws;
        wchi[i] = f2bf(w[(size_t)l * 65536 + rr * 256 + c]);
        return;
    }
    i -= 1048576;
    if (i < 4096) {
        int l = i >> 10, r = i & 1023;
        int seg = r >> 8, rr = r & 255;
        const float* b = seg == 0 ? bq : seg == 1 ? bk : seg == 2 ? bv : bs;
        bcat[i] = b[l * 256 + rr];
    }
}

// ---------------------------------------------------------------- CSR build
__global__ __launch_bounds__(256) void count_kernel(const int* __restrict__ ei,
                                                    int* __restrict__ deg) {
    int e = blockIdx.x * 256 + threadIdx.x;
    if (e < N_EDGES) atomicAdd(&deg[ei[N_EDGES + e]], 1);
}

// scan stage 1 + degree histogram (fused; same grid, both read deg)
__global__ __launch_bounds__(256) void scan1h_kernel(const int* __restrict__ deg,
                                                     int* __restrict__ indptr,
                                                     int* __restrict__ bsum,
                                                     int* __restrict__ blkcnt) {
    __shared__ int wsum[4];
    __shared__ int hloc[64];
    int tid = threadIdx.x, lane = tid & 63, wave = tid >> 6;
    if (tid < 64) hloc[tid] = 0;
    int i = blockIdx.x * 256 + tid;
    int v = deg[i];
    int x = v;
    #pragma unroll
    for (int off = 1; off < 64; off <<= 1) {
        int t = __shfl_up(x, off, 64);
        if (lane >= off) x += t;
    }
    if (lane == 63) wsum[wave] = x;
    int b = v > 63 ? 63 : v;
    __syncthreads();
    atomicAdd(&hloc[b], 1);                      // LDS atomic
    if (tid == 0) {
        int s = 0;
        #pragma unroll
        for (int w = 0; w < 4; ++w) { int t = wsum[w]; wsum[w] = s; s += t; }
        bsum[blockIdx.x] = s;
    }
    __syncthreads();
    indptr[i] = wsum[wave] + x - v;   // block-local exclusive prefix
    if (tid < 64) blkcnt[blockIdx.x * 64 + tid] = hloc[tid];
}

// stage 2 scans (fused): wave0 = block-sum scan, wave1 = bucket-base scan
__global__ __launch_bounds__(128) void scan2b_kernel(const int* __restrict__ bsum,
                                                     int* __restrict__ boff,
                                                     int* __restrict__ indptr,
                                                     const int* __restrict__ blkcnt,
                                                     int* __restrict__ gbase) {
    int tid = threadIdx.x;
    if (tid < 64) {
        int lane = tid;
        int carry = 0;
        for (int base = 0; base < N_SBLK; base += 64) {
            int i = base + lane;
            int v = (i < N_SBLK) ? bsum[i] : 0;
            int x = v;
            #pragma unroll
            for (int off = 1; off < 64; off <<= 1) {
                int t = __shfl_up(x, off, 64);
                if (lane >= off) x += t;
            }
            if (i < N_SBLK) boff[i] = carry + x - v;
            carry += __shfl(x, 63, 64);
        }
        if (lane == 0) indptr[N_NODES] = carry;
    } else {
        int b = tid - 64;
        int tot = 0;
        #pragma unroll 5
        for (int blk = 0; blk < N_SBLK; ++blk) tot += blkcnt[blk * 64 + b];
        int x = tot;
        #pragma unroll
        for (int off = 1; off < 64; off <<= 1) {
            int t = __shfl_up(x, off, 64);
            if (b >= off) x += t;
        }
        int running = x - tot;                   // exclusive bucket base
        #pragma unroll 5
        for (int blk = 0; blk < N_SBLK; ++blk) {
            int c = blkcnt[blk * 64 + b];
            gbase[blk * 64 + b] = running;
            running += c;
        }
    }
}

// stage 3 + permutation scatter (fused; same grid). Within-bucket order is
// non-deterministic but each node's computation is self-contained with fixed
// edge order -> output bits unaffected.
__global__ __launch_bounds__(256) void scan3p_kernel(const int* __restrict__ boff,
                                                     int* __restrict__ indptr,
                                                     int* __restrict__ cursor,
                                                     const int* __restrict__ deg,
                                                     const int* __restrict__ gbase,
                                                     int* __restrict__ perm) {
    __shared__ int cur[64];
    int tid = threadIdx.x;
    if (tid < 64) cur[tid] = gbase[blockIdx.x * 64 + tid];
    int i = blockIdx.x * 256 + tid;
    int val = indptr[i] + boff[blockIdx.x];
    indptr[i] = val;
    cursor[i] = val;
    __syncthreads();
    int b = deg[i]; if (b > 63) b = 63;
    int pos = atomicAdd(&cur[b], 1);             // LDS atomic
    perm[pos] = i;
}

__global__ __launch_bounds__(256) void scatter_kernel(const int* __restrict__ ei,
                                                      int* __restrict__ cursor,
                                                      int* __restrict__ ssrc) {
    int e = blockIdx.x * 256 + threadIdx.x;
    if (e < N_EDGES) {
        int dst = ei[N_EDGES + e];
        int pos = atomicAdd(&cursor[dst], 1);
        ssrc[pos] = ei[e];
    }
}

// ---------------------------------------------------------------- pe MLP stage 1
__global__ __launch_bounds__(256) void pe1_kernel(const float* __restrict__ lpe,
                                                  const float* __restrict__ w1,
                                                  const float* __restrict__ b1,
                                                  u16* __restrict__ t1b) {
    __shared__ float l[16];
    int n = blockIdx.x, j = threadIdx.x;
    if (j < 16) l[j] = lpe[n * 16 + j];
    __syncthreads();
    float s = b1[j];
    #pragma unroll
    for (int kk = 0; kk < 16; ++kk) s += l[kk] * w1[j * 16 + kk];
    t1b[(size_t)n * HID + j] = f2bf(fmaxf(s, 0.0f));
}

// ---------------------------------------------------------------- MFMA GEMM
// C[M x N] = A_bf16[M x K] @ W_bf16[N x K]^T + bias, f32 accumulate.
// BM=128, BN=256, BK=64, 8 waves (2 row x 4 col), wave tile 64x64 (4x4 frags).
// LDS row-major w/ column XOR swizzle; staging via global_load_lds w16.
// Epilogue: 4 row-group passes through LDS (32 x 268-padded f32), wide stores.
// MODE 0: C0 = val;  MODE 1: C0 += val;
// MODE 2 (QKVS, N=1024): col<256 -> qbx (f16); 256..767 -> khv head-sliced f16;
//                        >=768 -> skipb (f32)
// MODE 3: C0 += val, then row-LayerNorm -> qbx (bf16)   [fuses layer-0 LN]
template <int MODE>
__global__ __launch_bounds__(512) void mgemm(const u16* __restrict__ A,
                                             const u16* __restrict__ Wh,
                                             const float* __restrict__ bias,
                                             int K,
                                             float* __restrict__ C0,
                                             u16* __restrict__ qbx,
                                             u16* __restrict__ khv,
                                             float* __restrict__ skipb,
                                             const float* __restrict__ lng,
                                             const float* __restrict__ lnb) {
    __shared__ __align__(16) u16 smem[(128 + 256) * 64];   // sA | sWh, 48KB
    u16* sA  = smem;
    u16* sWh = smem + 128 * 64;
    const int tid = threadIdx.x;
    const int l = tid & 63, wid = tid >> 6;          // 8 waves
    const int wm = wid >> 2, wn = wid & 3;           // 2 x 4
    const int lr = l & 15, lc = l >> 4;
    const int r0 = blockIdx.y * 128;
    const int c0 = blockIdx.x * 256;

    f32x4 acc[4][4];
    #pragma unroll
    for (int m = 0; m < 4; ++m)
        #pragma unroll
        for (int n = 0; n < 4; ++n) acc[m][n] = (f32x4){0.f, 0.f, 0.f, 0.f};

    const int sr = l >> 3;                 // row within 8-row group
    const int skc = (l & 7) ^ sr;          // swizzled source column chunk
    for (int k0 = 0; k0 < K; k0 += 64) {
        #pragma unroll
        for (int j = 0; j < 2; ++j) {
            int grp = j * 8 + wid;
            int r = grp * 8 + sr;
            gll16(A + (size_t)(r0 + r) * K + k0 + skc * 8, sA + grp * 512);
        }
        #pragma unroll
        for (int j = 0; j < 4; ++j) {
            int grp = j * 8 + wid;
            int r = grp * 8 + sr;
            gll16(Wh + (size_t)(c0 + r) * K + k0 + skc * 8, sWh + grp * 512);
        }
        __syncthreads();
        #pragma unroll
        for (int kk = 0; kk < 2; ++kk) {
            const int kc = kk * 4 + lc;
            bf16x8 a[4], wh[4];
            #pragma unroll
            for (int m = 0; m < 4; ++m) {
                int r = wm * 64 + m * 16 + lr;
                a[m] = *reinterpret_cast<const bf16x8*>(
                    &sA[r * 64 + ((kc ^ (r & 7)) * 8)]);
            }
            #pragma unroll
            for (int n = 0; n < 4; ++n) {
                int r = wn * 64 + n * 16 + lr;
                wh[n] = *reinterpret_cast<const bf16x8*>(
                    &sWh[r * 64 + ((kc ^ (r & 7)) * 8)]);
            }
            #pragma unroll
            for (int m = 0; m < 4; ++m)
                #pragma unroll
                for (int n = 0; n < 4; ++n)
                    acc[m][n] = __builtin_amdgcn_mfma_f32_16x16x32_bf16(a[m], wh[n], acc[m][n], 0, 0, 0);
        }
        __syncthreads();
    }

    // ---- epilogue: 4 row-group passes; full-row wide stores ----
    float* sC = reinterpret_cast<float*>(smem);     // 32 x 268 f32 = 34.3KB
    const int lrr = tid >> 4;                       // 0..31 local row (readout)
    const int cseg = (tid & 15) * 16;               // 16-col segment base
    #pragma unroll
    for (int m = 0; m < 4; ++m) {
        __syncthreads();
        #pragma unroll
        for (int n = 0; n < 4; ++n) {
            #pragma unroll
            for (int i = 0; i < 4; ++i) {
                int lro = wm * 16 + lc * 4 + i;
                sC[lro * 268 + wn * 64 + n * 16 + lr] = acc[m][n][i];
            }
        }
        __syncthreads();
        int row = r0 + (lrr >> 4) * 64 + m * 16 + (lrr & 15);
        int col = c0 + cseg;
        f32x4 v[4];
        #pragma unroll
        for (int s = 0; s < 4; ++s) {
            v[s] = *reinterpret_cast<const f32x4*>(&sC[lrr * 268 + cseg + s * 4]);
            v[s] += *reinterpret_cast<const f32x4*>(&bias[col + s * 4]);
        }
        if (MODE == 0) {
            float* p = &C0[(size_t)row * 256 + col];
            #pragma unroll
            for (int s = 0; s < 4; ++s) *reinterpret_cast<f32x4*>(p + s * 4) = v[s];
        } else if (MODE == 1) {
            float* p = &C0[(size_t)row * 256 + col];
            #pragma unroll
            for (int s = 0; s < 4; ++s) {
                f32x4 o = *reinterpret_cast<const f32x4*>(p + s * 4);
                *reinterpret_cast<f32x4*>(p + s * 4) = v[s] + o;
            }
        } else if (MODE == 3) {
            float* p = &C0[(size_t)row * 256 + col];
            #pragma unroll
            for (int s = 0; s < 4; ++s) {
                f32x4 o = *reinterpret_cast<const f32x4*>(p + s * 4);
                v[s] += o;
                *reinterpret_cast<f32x4*>(p + s * 4) = v[s];
            }
            // row LayerNorm across the 16 threads sharing this row
            float sum = 0.f;
            #pragma unroll
            for (int s = 0; s < 4; ++s)
                sum += v[s][0] + v[s][1] + v[s][2] + v[s][3];
            #pragma unroll
            for (int off = 1; off < 16; off <<= 1) sum += __shfl_xor(sum, off, 64);
            float mu = sum * (1.0f / 256.0f);
            float qq = 0.f;
            #pragma unroll
            for (int s = 0; s < 4; ++s)
                #pragma unroll
                for (int j2 = 0; j2 < 4; ++j2) { float d = v[s][j2] - mu; qq += d * d; }
            #pragma unroll
            for (int off = 1; off < 16; off <<= 1) qq += __shfl_xor(qq, off, 64);
            float invs = rsqrtf(qq * (1.0f / 256.0f) + 1e-5f);
            u16x8 o0, o1;
            #pragma unroll
            for (int j2 = 0; j2 < 4; ++j2) {
                o0[j2]     = f2bf((v[0][j2] - mu) * invs * lng[col + j2]      + lnb[col + j2]);
                o0[4 + j2] = f2bf((v[1][j2] - mu) * invs * lng[col + 4 + j2]  + lnb[col + 4 + j2]);
                o1[j2]     = f2bf((v[2][j2] - mu) * invs * lng[col + 8 + j2]  + lnb[col + 8 + j2]);
                o1[4 + j2] = f2bf((v[3][j2] - mu) * invs * lng[col + 12 + j2] + lnb[col + 12 + j2]);
            }
            u16* px = &qbx[(size_t)row * 256 + col];
            *reinterpret_cast<u16x8*>(px) = o0;
            *reinterpret_cast<u16x8*>(px + 8) = o1;
        } else {
            if (col < 256) {
                u16x8 o0, o1;
                #pragma unroll
                for (int j = 0; j < 4; ++j) {
                    o0[j] = f2h(v[0][j]); o0[4 + j] = f2h(v[1][j]);
                    o1[j] = f2h(v[2][j]); o1[4 + j] = f2h(v[3][j]);
                }
                u16* p = &qbx[(size_t)row * 256 + col];
                *reinterpret_cast<u16x8*>(p) = o0;
                *reinterpret_cast<u16x8*>(p + 8) = o1;
            } else if (col < 768) {
                int cc = col - (col < 512 ? 256 : 512);
                int hh = cc >> 5, ch = cc & 31;
                int vo = (col < 512) ? 0 : 32;
                u16x8 o0, o1;
                #pragma unroll
                for (int j = 0; j < 4; ++j) {
                    o0[j] = f2h(v[0][j]); o0[4 + j] = f2h(v[1][j]);
                    o1[j] = f2h(v[2][j]); o1[4 + j] = f2h(v[3][j]);
                }
                u16* p = &khv[((size_t)hh * N_NODES + row) * 64 + vo + ch];
                *reinterpret_cast<u16x8*>(p) = o0;
                *reinterpret_cast<u16x8*>(p + 8) = o1;
            } else {
                float* p = &skipb[(size_t)row * 256 + (col - 768)];
                #pragma unroll
                for (int s = 0; s < 4; ++s) *reinterpret_cast<f32x4*>(p + s * 4) = v[s];
            }
        }
    }
}

// ---------------------------------------------------------------- fused edge attention
// one 4-lane group per (perm-node, head); degree-sorted perm -> groups in a
// wave have near-equal edge counts. Per-group LDS index staging. f16 k/v with
// fdot2 QK.
__global__ __launch_bounds__(256) void agg_kernel(const u16* __restrict__ qb,
                                                  const u16* __restrict__ khv,
                                                  const int* __restrict__ indptr,
                                                  const int* __restrict__ ssrc,
                                                  const int* __restrict__ perm,
                                                  float* __restrict__ outb) {
    __shared__ int sIdx[MAX_SIDX];
    __shared__ int loff_s[64];
    const float scale = 0.17677669529663687f;  // 1/sqrt(32)
    const int tid = threadIdx.x;
    const int g = tid >> 2;     // group 0..63
    const int j = tid & 3;      // channel quad (8 ch) within head
    const int h = blockIdx.x & 7;
    const int nb = (blockIdx.x >> 3) * 64;
    const int n = perm[nb + g];

    // block-local exclusive scan of the 64 node degrees (wave 0)
    if (tid < 64) {
        int pn = perm[nb + tid];
        int d = indptr[pn + 1] - indptr[pn];
        int x = d;
        #pragma unroll
        for (int off = 1; off < 64; off <<= 1) {
            int t = __shfl_up(x, off, 64);
            if (tid >= off) x += t;
        }
        loff_s[tid] = x - d;
    }
    __syncthreads();

    const int s0 = indptr[n], s1 = indptr[n + 1];
    const int dg = s1 - s0;
    const int myoff = loff_s[g];
    const bool staged = (myoff + dg) <= MAX_SIDX;
    if (staged) {
        for (int i = j; i < dg; i += 4)
            sIdx[myoff + i] = ssrc[s0 + i];
    }
    __syncthreads();

    u16x8 q8 = *reinterpret_cast<const u16x8*>(qb + (size_t)n * HID + h * 32 + j * 8);
    h16x2 qp[4];
    #pragma unroll
    for (int i = 0; i < 4; ++i)
        qp[i] = *(reinterpret_cast<const h16x2*>(&q8) + i);

    const int last = s1 - 1;
    const u16* base = khv + (size_t)h * N_NODES * 64 + j * 8;
    float acc[8] = {0.f, 0.f, 0.f, 0.f, 0.f, 0.f, 0.f, 0.f};
    float ssum = 0.f;

    if (s0 < s1) {
        const int nchunk = (dg + 3) >> 2;
        const int npair = (nchunk + 1) >> 1;
        int iA[4], iB[4];
        u16x8 kA[4], vA[4], kB[4], vB[4];
        #define LDIDX(e_, dst_) { int e2 = (e_) > last ? last : (e_); \
            dst_ = staged ? sIdx[myoff + (e2 - s0)] \
                          : __builtin_nontemporal_load(&ssrc[e2]); }
        #define QKDOT(kreg_, prod_) { \
            const h16x2* kp = reinterpret_cast<const h16x2*>(&kreg_); \
            prod_ = __builtin_amdgcn_fdot2(qp[0], kp[0], 0.0f, false); \
            prod_ = __builtin_amdgcn_fdot2(qp[1], kp[1], prod_, false); \
            prod_ = __builtin_amdgcn_fdot2(qp[2], kp[2], prod_, false); \
            prod_ = __builtin_amdgcn_fdot2(qp[3], kp[3], prod_, false); }
        #pragma unroll
        for (int i = 0; i < 4; ++i) LDIDX(s0 + i, iA[i]);
        #pragma unroll
        for (int i = 0; i < 4; ++i) {
            const u16* rp = base + (size_t)iA[i] * 64;
            kA[i] = *reinterpret_cast<const u16x8*>(rp);
            vA[i] = *reinterpret_cast<const u16x8*>(rp + 32);
        }
        #pragma unroll
        for (int i = 0; i < 4; ++i) LDIDX(s0 + 4 + i, iB[i]);
        int eb = s0;
        for (int pc = 0; pc < npair; ++pc) {
            #pragma unroll
            for (int i = 0; i < 4; ++i) {
                const u16* rp = base + (size_t)iB[i] * 64;
                kB[i] = *reinterpret_cast<const u16x8*>(rp);
                vB[i] = *reinterpret_cast<const u16x8*>(rp + 32);
            }
            #pragma unroll
            for (int i = 0; i < 4; ++i) {
                float prod;
                QKDOT(kA[i], prod);
                prod += __shfl_xor(prod, 1, 64);
                prod += __shfl_xor(prod, 2, 64);
                float p = (eb + i <= last) ? __expf(prod * scale) : 0.f;
                ssum += p;
                #pragma unroll
                for (int t = 0; t < 8; ++t) acc[t] += p * h2f(vA[i][t]);
            }
            eb += 4;
            #pragma unroll
            for (int i = 0; i < 4; ++i) LDIDX(eb + 4 + i, iA[i]);
            #pragma unroll
            for (int i = 0; i < 4; ++i) {
                const u16* rp = base + (size_t)iA[i] * 64;
                kA[i] = *reinterpret_cast<const u16x8*>(rp);
                vA[i] = *reinterpret_cast<const u16x8*>(rp + 32);
            }
            #pragma unroll
            for (int i = 0; i < 4; ++i) {
                float prod;
                QKDOT(kB[i], prod);
                prod += __shfl_xor(prod, 1, 64);
                prod += __shfl_xor(prod, 2, 64);
                float p = (eb + i <= last) ? __expf(prod * scale) : 0.f;
                ssum += p;
                #pragma unroll
                for (int t = 0; t < 8; ++t) acc[t] += p * h2f(vB[i][t]);
            }
            eb += 4;
            #pragma unroll
            for (int i = 0; i < 4; ++i) LDIDX(eb + 4 + i, iB[i]);
        }
        #undef QKDOT
        #undef LDIDX
    }

    float inv = 1.0f / fmaxf(ssum, 1e-16f);
    float* op = outb + (size_t)n * HID + h * 32 + j * 8;
    f32x4 o0 = {acc[0] * inv, acc[1] * inv, acc[2] * inv, acc[3] * inv};
    f32x4 o1 = {acc[4] * inv, acc[5] * inv, acc[6] * inv, acc[7] * inv};
    __builtin_nontemporal_store(o0, (f32x4*)op);
    __builtin_nontemporal_store(o1, (f32x4*)(op + 4));
}

// ------------------------------------------- beta gate + relu + residual (+ next LN)
template <bool DO_LN>
__global__ __launch_bounds__(256) void beta_kernel(const float* __restrict__ outb,
                                                   const float* __restrict__ skipb,
                                                   const float* __restrict__ wb,
                                                   const float* __restrict__ gw,
                                                   const float* __restrict__ bw,
                                                   float* __restrict__ h,
                                                   u16* __restrict__ xnb) {
    int lane = threadIdx.x & 63, wave = threadIdx.x >> 6;
    int node = blockIdx.x * 4 + wave;
    int c = lane * 4;
    float4 o  = ((const float4*)(outb  + (size_t)node * HID))[lane];
    float4 sk = ((const float4*)(skipb + (size_t)node * HID))[lane];
    float acc = o.x * wb[c + 0] + o.y * wb[c + 1] + o.z * wb[c + 2] + o.w * wb[c + 3]
              + sk.x * wb[HID + c + 0] + sk.y * wb[HID + c + 1]
              + sk.z * wb[HID + c + 2] + sk.w * wb[HID + c + 3]
              + (o.x - sk.x) * wb[2 * HID + c + 0] + (o.y - sk.y) * wb[2 * HID + c + 1]
              + (o.z - sk.z) * wb[2 * HID + c + 2] + (o.w - sk.w) * wb[2 * HID + c + 3];
    #pragma unroll
    for (int off = 32; off; off >>= 1) acc += __shfl_xor(acc, off, 64);
    float beta = 1.0f / (1.0f + __expf(-acc));
    float4 r = ((const float4*)(h + (size_t)node * HID))[lane];
    float4 out;
    out.x = fmaxf(beta * sk.x + (1.0f - beta) * o.x, 0.0f) + r.x;
    out.y = fmaxf(beta * sk.y + (1.0f - beta) * o.y, 0.0f) + r.y;
    out.z = fmaxf(beta * sk.z + (1.0f - beta) * o.z, 0.0f) + r.z;
    out.w = fmaxf(beta * sk.w + (1.0f - beta) * o.w, 0.0f) + r.w;
    ((float4*)(h + (size_t)node * HID))[lane] = out;

    if (DO_LN) {
        float s = out.x + out.y + out.z + out.w;
        #pragma unroll
        for (int off = 32; off; off >>= 1) s += __shfl_xor(s, off, 64);
        float mu = s * (1.0f / HID);
        float dx = out.x - mu, dy = out.y - mu, dz = out.z - mu, dw = out.w - mu;
        float qq = dx * dx + dy * dy + dz * dz + dw * dw;
        #pragma unroll
        for (int off = 32; off; off >>= 1) qq += __shfl_xor(qq, off, 64);
        float inv = rsqrtf(qq * (1.0f / HID) + 1e-5f);
        float o0 = dx * inv * gw[c + 0] + bw[c + 0];
        float o1 = dy * inv * gw[c + 1] + bw[c + 1];
        float o2 = dz * inv * gw[c + 2] + bw[c + 2];
        float o3 = dw * inv * gw[c + 3] + bw[c + 3];
        uint2 pk;
        pk.x = (unsigned int)f2bf(o0) | ((unsigned int)f2bf(o1) << 16);
        pk.y = (unsigned int)f2bf(o2) | ((unsigned int)f2bf(o3) << 16);
        *reinterpret_cast<uint2*>(xnb + (size_t)node * HID + c) = pk;
    }
}

// ---------------------------------------------------------------- pooling + final MLP
// stage 1: 16 chunks per graph, deterministic partials pxg[g][chunk][256]
__global__ __launch_bounds__(256) void pool_kernel(const float* __restrict__ h,
                                                   const int* __restrict__ batch,
                                                   float* __restrict__ pxg) {
    int gb = blockIdx.x;                 // 0 .. N_GRAPHS*P_CHUNK-1
    int g = gb >> 4, cch = gb & (P_CHUNK - 1);
    int t = threadIdx.x;
    int s = lbound_batch(batch, g), e = lbound_batch(batch, g + 1);
    float acc = 0.0f;
    for (int i = s + cch; i < e; i += P_CHUNK)
        acc += __builtin_nontemporal_load(&h[(size_t)i * HID + t]);
    pxg[(size_t)gb * HID + t] = acc;
}

__global__ __launch_bounds__(256) void mlp_kernel(const float* __restrict__ pxg,
                                                  const int* __restrict__ batch,
                                                  const float* __restrict__ w1,
                                                  const float* __restrict__ b1,
                                                  const float* __restrict__ w2,
                                                  const float* __restrict__ b2,
                                                  float* __restrict__ out) {
    __shared__ float xr[256];
    __shared__ float red[256];
    int g = blockIdx.x, t = threadIdx.x;
    float sum = 0.0f;
    #pragma unroll
    for (int c = 0; c < P_CHUNK; ++c)
        sum += pxg[((size_t)g * P_CHUNK + c) * HID + t];
    float cnt = (float)(lbound_batch(batch, g + 1) - lbound_batch(batch, g));
    xr[t] = sum / fmaxf(cnt, 1.0f);
    __syncthreads();
    float s = b1[t];
    #pragma unroll 4
    for (int kk = 0; kk < 256; ++kk) s += xr[kk] * w1[t * 256 + kk];
    s = fmaxf(s, 0.0f);
    red[t] = s * w2[t];
    __syncthreads();
    for (int off = 128; off; off >>= 1) {
        if (t < off) red[t] += red[t + off];
        __syncthreads();
    }
    if (t == 0) out[g] = red[0] + b2[0];
}

// ---------------------------------------------------------------- host
extern "C" void kernel_launch(void* const* d_in, const int* in_sizes, int n_in,
                              void* d_out, int out_size, void* d_ws, size_t ws_size,
                              hipStream_t stream) {
    const float* x      = (const float*)d_in[0];
    const float* lpe    = (const float*)d_in[1];
    const float* pe_w1  = (const float*)d_in[2];
    const float* pe_b1  = (const float*)d_in[3];
    const float* pe_w2  = (const float*)d_in[4];
    const float* pe_b2  = (const float*)d_in[5];
    const float* emb_w  = (const float*)d_in[6];
    const float* emb_b  = (const float*)d_in[7];
    const float* ln_g   = (const float*)d_in[8];
    const float* ln_b   = (const float*)d_in[9];
    const float* wq     = (const float*)d_in[10];
    const float* bq     = (const float*)d_in[11];
    const float* wk     = (const float*)d_in[12];
    const float* bk     = (const float*)d_in[13];
    const float* wv     = (const float*)d_in[14];
    const float* bv     = (const float*)d_in[15];
    const float* wskip  = (const float*)d_in[16];
    const float* bskip  = (const float*)d_in[17];
    const float* wbeta  = (const float*)d_in[18];
    const float* mlp_w1 = (const float*)d_in[19];
    const float* mlp_b1 = (const float*)d_in[20];
    const float* mlp_w2 = (const float*)d_in[21];
    const float* mlp_b2 = (const float*)d_in[22];
    const int*   eidx   = (const int*)d_in[23];
    const int*   batch  = (const int*)d_in[24];

    char* w = (char*)d_ws;
    const size_t NH = (size_t)N_NODES * HID;
    float* h     = (float*)w;           w += NH * 4;
    float* skipb = (float*)w;           w += NH * 4;
    float* outb  = (float*)w;           w += NH * 4;
    float* pxg   = (float*)w;           w += (size_t)N_GRAPHS * P_CHUNK * HID * 4;
    u16* qb      = (u16*)w;             w += NH * 2;
    u16* xnb     = (u16*)w;             w += NH * 2;
    u16* khv     = (u16*)w;             w += (size_t)HEADS * N_NODES * 64 * 2;
    u16* xb      = (u16*)w;             w += (size_t)N_NODES * IN_CH * 2;
    u16* t1b     = (u16*)w;             w += NH * 2;
    u16* ehi     = (u16*)w;             w += 32768 * 2;
    u16* p2hi    = (u16*)w;             w += 65536 * 2;
    u16* wchi    = (u16*)w;             w += 1048576 * 2;
    float* bcat  = (float*)w;           w += 4096 * 4;
    int* deg     = (int*)w;             w += N_NODES * 4;
    int* indptr  = (int*)w;             w += (N_NODES + 1) * 4;
    int* cursor  = (int*)w;             w += N_NODES * 4;
    int* ssrc    = (int*)w;             w += N_EDGES * 4;
    int* bsum    = (int*)w;             w += 128 * 4;
    int* boff    = (int*)w;             w += 128 * 4;
    int* blkcnt  = (int*)w;             w += N_SBLK * 64 * 4;
    int* gbase   = (int*)w;             w += N_SBLK * 64 * 4;
    int* perm    = (int*)w;             w += N_NODES * 4;

    // fused conversions (1 dispatch)
    prep_kernel<<<20497, 256, 0, stream>>>(x, emb_w, pe_w2, wq, wk, wv, wskip,
                                           bq, bk, bv, bskip,
                                           xb, ehi, p2hi, wchi, bcat);

    // CSR + degree-bucketed permutation (fused stages)
    hipMemsetAsync(deg, 0, N_NODES * sizeof(int), stream);
    count_kernel<<<(N_EDGES + 255) / 256, 256, 0, stream>>>(eidx, deg);
    scan1h_kernel<<<N_SBLK, 256, 0, stream>>>(deg, indptr, bsum, blkcnt);
    scan2b_kernel<<<1, 128, 0, stream>>>(bsum, boff, indptr, blkcnt, gbase);
    scan3p_kernel<<<N_SBLK, 256, 0, stream>>>(boff, indptr, cursor, deg, gbase, perm);
    scatter_kernel<<<(N_EDGES + 255) / 256, 256, 0, stream>>>(eidx, cursor, ssrc);

    // h = x@emb_w^T + emb_b + pe_mlp(lpe); layer-0 LN fused into mgemm<3>
    pe1_kernel<<<N_NODES, 256, 0, stream>>>(lpe, pe_w1, pe_b1, t1b);
    mgemm<0><<<dim3(1, 250), 512, 0, stream>>>(xb, ehi, emb_b, IN_CH, h,
                                               nullptr, nullptr, nullptr, nullptr, nullptr);
    mgemm<3><<<dim3(1, 250), 512, 0, stream>>>(t1b, p2hi, pe_b2, HID, h,
                                               xnb, nullptr, nullptr, ln_g, ln_b);

    for (int l = 0; l < N_LAYERS; ++l) {
        mgemm<2><<<dim3(4, 250), 512, 0, stream>>>(xnb, wchi + (size_t)l * 262144,
                                                   bcat + l * 1024, HID,
                                                   nullptr, qb, khv, skipb, nullptr, nullptr);
        agg_kernel<<<(N_NODES / 64) * 8, 256, 0, stream>>>(qb, khv, indptr, ssrc, perm, outb);
        if (l < N_LAYERS - 1) {
            beta_kernel<true><<<N_NODES / 4, 256, 0, stream>>>(
                outb, skipb, wbeta + l * 3 * HID,
                ln_g + (l + 1) * HID, ln_b + (l + 1) * HID, h, xnb);
        } else {
            beta_kernel<false><<<N_NODES / 4, 256, 0, stream>>>(
                outb, skipb, wbeta + l * 3 * HID, nullptr, nullptr, h, nullptr);
        }
    }

    pool_kernel<<<N_GRAPHS * P_CHUNK, 256, 0, stream>>>(h, batch, pxg);
    mlp_kernel<<<N_GRAPHS, 256, 0, stream>>>(pxg, batch, mlp_w1, mlp_b1, mlp_w2, mlp_b2, (float*)d_out);
}